// Round 2
// baseline (456.541 us; speedup 1.0000x reference)
//
#include <hip/hip_runtime.h>

// ---------------- problem constants ----------------
constexpr int NB = 16;       // batch
constexpr int SS = 64;       // seq len
constexpr int BS = 1024;     // NB*SS
constexpr int NN = 500;      // nodes
constexpr int FF = 32;       // gat out features
constexpr int EE = 8000;     // edges (without self loops)
constexpr int ET = 8500;     // edges + self loops
constexpr int KK = 16000;    // NN*FF  (lstm input size)
constexpr int HH = 128;      // lstm hidden
constexpr int GG = 512;      // 4*HH
constexpr int KS = 4;        // K-split for the big GEMM

// ---------------- prep kernels ----------------

// xt[n][bs] = x[bs][n]   (x is [B,S,N] row-major, bs = b*S+s)
__global__ void k_transpose_x(const float* __restrict__ x, float* __restrict__ xt) {
    __shared__ float tile[32][33];
    int n0 = blockIdx.x * 32, bs0 = blockIdx.y * 32;
    int tx = threadIdx.x, ty = threadIdx.y;  // 32 x 8
#pragma unroll
    for (int i = 0; i < 4; ++i) {
        int n = n0 + tx, bs = bs0 + ty + i * 8;
        tile[ty + i * 8][tx] = (n < NN) ? x[bs * NN + n] : 0.f;
    }
    __syncthreads();
#pragma unroll
    for (int i = 0; i < 4; ++i) {
        int n = n0 + ty + i * 8, bs = bs0 + tx;
        if (n < NN) xt[n * BS + bs] = tile[tx][ty + i * 8];
    }
}

// w_hh_t[j][g] = w_hh[g][j]   (512x128 -> 128x512)
__global__ void k_whh_t(const float* __restrict__ whh, float* __restrict__ wt) {
    int idx = blockIdx.x * 256 + threadIdx.x;  // 65536 total
    int j = idx >> 9, g = idx & 511;
    wt[idx] = whh[g * HH + j];
}

// count in-degrees (incl self loops), exclusive-scan -> offsets[501], cursor, and ws/wd scalars
__global__ void k_count_scan(const int* __restrict__ ei,
                             const float* __restrict__ gat_w, const float* __restrict__ a_src,
                             const float* __restrict__ a_dst,
                             int* __restrict__ offsets, int* __restrict__ cursor,
                             float* __restrict__ scal) {
    __shared__ int cnt[512];
    __shared__ int sc[2][512];
    int t = threadIdx.x;  // 512 threads
    cnt[t] = 0;
    __syncthreads();
    for (int e = t; e < ET; e += 512) {
        int d = (e < EE) ? ei[EE + e] : (e - EE);
        atomicAdd(&cnt[d], 1);
    }
    __syncthreads();
    sc[0][t] = cnt[t];
    __syncthreads();
    int pb = 0;
    for (int off = 1; off < 512; off <<= 1) {
        int v = sc[pb][t];
        if (t >= off) v += sc[pb][t - off];
        sc[pb ^ 1][t] = v;
        pb ^= 1;
        __syncthreads();
    }
    int inc = sc[pb][t];
    int excl = inc - cnt[t];
    if (t <= NN) offsets[t] = excl;   // offsets[500] = total = ET
    if (t < NN) cursor[t] = excl;
    if (t == 0) {
        float ws = 0.f, wd = 0.f;
        for (int f = 0; f < FF; ++f) {
            ws += gat_w[f] * a_src[f];
            wd += gat_w[f] * a_dst[f];
        }
        scal[0] = ws;
        scal[1] = wd;
    }
}

// scatter edge sources into dst-sorted buckets
__global__ void k_scatter(const int* __restrict__ ei, int* __restrict__ cursor,
                          int* __restrict__ esrc) {
    int e = blockIdx.x * 256 + threadIdx.x;
    if (e >= ET) return;
    int sidx = (e < EE) ? ei[e] : (e - EE);
    int d = (e < EE) ? ei[EE + e] : (e - EE);
    int pos = atomicAdd(&cursor[d], 1);
    esrc[pos] = sidx;
}

// ---------------- GAT: per-(n,bs) edge softmax -> s[n][bs] ----------------
__global__ void k_gat(const float* __restrict__ xt, const int* __restrict__ offsets,
                      const int* __restrict__ esrc, const float* __restrict__ scal,
                      float* __restrict__ s) {
    int n = blockIdx.y;
    int bs = blockIdx.x * 256 + threadIdx.x;
    float ws = scal[0], wd = scal[1];
    float xd = xt[n * BS + bs];
    float wdxd = wd * xd;
    int e0 = offsets[n], e1 = offsets[n + 1];
    float m = -1e30f, den = 0.f, num = 0.f;
    for (int j = e0; j < e1; ++j) {
        int sidx = esrc[j];  // uniform across warp
        float xs = xt[sidx * BS + bs];
        float z = ws * xs + wdxd;
        float l = (z > 0.f) ? z : 0.2f * z;  // leaky_relu 0.2
        if (l > m) {
            float r = __expf(m - l);
            den *= r;
            num *= r;
            m = l;
        }
        float p = __expf(l - m);
        den += p;
        num += p * xs;
    }
    s[n * BS + bs] = num / den;
}

// ---------------- big GEMM: G[ks][bs][g] = partial sum over K ----------------
// A[bs][k] = relu(s[k>>5][bs]*w[k&31] + b[k&31]) expanded on the fly.
__global__ __launch_bounds__(256) void k_gemm(const float* __restrict__ w_ih,
                                              const float* __restrict__ s,
                                              const float* __restrict__ gat_w,
                                              const float* __restrict__ gat_b,
                                              float* __restrict__ G2) {
    __shared__ __align__(16) float As[32][68];
    __shared__ __align__(16) float Bs[32][68];
    __shared__ float wb[FF], bb[FF];
    int tid = threadIdx.x;
    int bm = blockIdx.x;  // 16
    int bn = blockIdx.y;  // 8
    int ks = blockIdx.z;  // KS
    if (tid < FF) {
        wb[tid] = gat_w[tid];
        bb[tid] = gat_b[tid];
    }
    __syncthreads();
    const int KH = KK / KS;  // 4000
    int k0base = ks * KH;
    int bs0 = bm * 64, g0 = bn * 64;
    float acc[4][4] = {};
    int tn = tid & 15, tm = tid >> 4;        // compute tile: tm rows(bs), tn cols(g)
    int lr = tid & 7, brow = tid >> 3;       // B staging: 8 float4 per row of 32 k
    int am = tid & 63, af0 = (tid >> 6) * 8; // A staging

    for (int it = 0; it < KH / 32; ++it) {
        int k0 = k0base + it * 32;
        int n = k0 >> 5;  // BK=32 aligned -> single node per tile
        // stage B (transposed): Bs[kk][g] = w_ih[g0+g][k0+kk]
#pragma unroll
        for (int p = 0; p < 2; ++p) {
            int g = brow + p * 32;
            float4 v = *(const float4*)&w_ih[(size_t)(g0 + g) * KK + k0 + lr * 4];
            Bs[lr * 4 + 0][g] = v.x;
            Bs[lr * 4 + 1][g] = v.y;
            Bs[lr * 4 + 2][g] = v.z;
            Bs[lr * 4 + 3][g] = v.w;
        }
        // stage A: As[f][m] = relu(s[n][bs0+m]*w[f]+b[f])
        float sv = s[n * BS + bs0 + am];
#pragma unroll
        for (int f = 0; f < 8; ++f) {
            int ff = af0 + f;
            float v = sv * wb[ff] + bb[ff];
            As[ff][am] = (v > 0.f) ? v : 0.f;
        }
        __syncthreads();
#pragma unroll
        for (int kk = 0; kk < 32; ++kk) {
            float4 av = *(const float4*)&As[kk][tm * 4];
            float4 bv = *(const float4*)&Bs[kk][tn * 4];
            float a[4] = {av.x, av.y, av.z, av.w};
            float b[4] = {bv.x, bv.y, bv.z, bv.w};
#pragma unroll
            for (int i = 0; i < 4; ++i)
#pragma unroll
                for (int j = 0; j < 4; ++j) acc[i][j] += a[i] * b[j];
        }
        __syncthreads();
    }
    float* Gp = G2 + ((size_t)ks * BS + bs0) * GG + g0;
#pragma unroll
    for (int i = 0; i < 4; ++i) {
        float4 v = {acc[i][0], acc[i][1], acc[i][2], acc[i][3]};
        *(float4*)&Gp[(tm * 4 + i) * GG + tn * 4] = v;
    }
}

// ---------------- LSTM (16 independent chains) + head ----------------
__global__ __launch_bounds__(512) void k_lstm_head(const float* __restrict__ G2,
                                                   const float* __restrict__ b_ih,
                                                   const float* __restrict__ b_hh,
                                                   const float* __restrict__ wt,  // [128][512]
                                                   const float* __restrict__ head_w,
                                                   const float* __restrict__ head_b,
                                                   float* __restrict__ out) {
    __shared__ __align__(16) float h_lds[HH];
    __shared__ float gates[GG];
    int tid = threadIdx.x;  // 512
    int b = blockIdx.x;     // 16
    float wreg[HH];
#pragma unroll
    for (int j = 0; j < HH; ++j) wreg[j] = wt[j * GG + tid];
    float bias = b_ih[tid] + b_hh[tid];
    float c = 0.f;
    if (tid < HH) h_lds[tid] = 0.f;
    __syncthreads();
    for (int t = 0; t < SS; ++t) {
        size_t row = (size_t)(b * SS + t) * GG + tid;
        float acc = bias + G2[row] + G2[(size_t)BS * GG + row] + G2[2 * (size_t)BS * GG + row] +
                    G2[3 * (size_t)BS * GG + row];
        const float4* h4 = (const float4*)h_lds;
#pragma unroll
        for (int j4 = 0; j4 < HH / 4; ++j4) {
            float4 hv = h4[j4];
            acc += wreg[j4 * 4 + 0] * hv.x + wreg[j4 * 4 + 1] * hv.y + wreg[j4 * 4 + 2] * hv.z +
                   wreg[j4 * 4 + 3] * hv.w;
        }
        gates[tid] = acc;
        __syncthreads();
        if (tid < HH) {
            float ig = gates[tid], fg = gates[HH + tid], gg = gates[2 * HH + tid],
                  og = gates[3 * HH + tid];
            float si = 1.f / (1.f + __expf(-ig));
            float sf = 1.f / (1.f + __expf(-fg));
            float so = 1.f / (1.f + __expf(-og));
            c = sf * c + si * tanhf(gg);
            h_lds[tid] = so * tanhf(c);
        }
        __syncthreads();
    }
    // head: out[b][n] = head_b[n] + sum_j h[j]*head_w[n][j]
    if (tid < NN) {
        float acc = head_b[tid];
        const float4* h4 = (const float4*)h_lds;
        const float4* w4 = (const float4*)&head_w[tid * HH];
#pragma unroll
        for (int j4 = 0; j4 < HH / 4; ++j4) {
            float4 hv = h4[j4];
            float4 wv = w4[j4];
            acc += wv.x * hv.x + wv.y * hv.y + wv.z * hv.z + wv.w * hv.w;
        }
        out[b * NN + tid] = acc;
    }
}

// ---------------- launch ----------------
extern "C" void kernel_launch(void* const* d_in, const int* in_sizes, int n_in, void* d_out,
                              int out_size, void* d_ws, size_t ws_size, hipStream_t stream) {
    const float* x = (const float*)d_in[0];
    const int* ei = (const int*)d_in[1];   // harness passes integer inputs as int32
    const float* gat_w = (const float*)d_in[2];
    const float* a_src = (const float*)d_in[3];
    const float* a_dst = (const float*)d_in[4];
    const float* gat_b = (const float*)d_in[5];
    const float* w_ih = (const float*)d_in[6];
    const float* w_hh = (const float*)d_in[7];
    const float* b_ih = (const float*)d_in[8];
    const float* b_hh = (const float*)d_in[9];
    const float* head_w = (const float*)d_in[10];
    const float* head_b = (const float*)d_in[11];
    float* out = (float*)d_out;

    char* ws = (char*)d_ws;
    float* xt = (float*)(ws + 0);                      // 500*1024*4   = 2,048,000
    float* s = (float*)(ws + (2u << 20));              // 500*1024*4   = 2,048,000
    float* G2 = (float*)(ws + (4u << 20));             // 4*1024*512*4 = 8,388,608
    float* wt = (float*)(ws + (4u << 20) + 8388608u);  // 128*512*4    = 262,144
    char* base2 = ws + (4u << 20) + 8388608u + 262144u;
    int* offsets = (int*)(base2);           // 501 ints
    int* cursor = (int*)(base2 + 4096);     // 500 ints
    int* esrc = (int*)(base2 + 8192);       // 8500 ints
    float* scal = (float*)(base2 + 45056);  // 2 floats

    k_transpose_x<<<dim3(16, 32), dim3(32, 8), 0, stream>>>(x, xt);
    k_whh_t<<<256, 256, 0, stream>>>(w_hh, wt);
    k_count_scan<<<1, 512, 0, stream>>>(ei, gat_w, a_src, a_dst, offsets, cursor, scal);
    k_scatter<<<(ET + 255) / 256, 256, 0, stream>>>(ei, cursor, esrc);
    k_gat<<<dim3(BS / 256, NN), 256, 0, stream>>>(xt, offsets, esrc, scal, s);
    k_gemm<<<dim3(16, 8, KS), 256, 0, stream>>>(w_ih, s, gat_w, gat_b, G2);
    k_lstm_head<<<NB, 512, 0, stream>>>(G2, b_ih, b_hh, wt, head_w, head_b, out);
}

// Round 3
// 324.367 us; speedup vs baseline: 1.4075x; 1.4075x over previous
//
#include <hip/hip_runtime.h>
#include <hip/hip_bf16.h>

// ---------------- problem constants ----------------
constexpr int NB = 16;       // batch
constexpr int SS = 64;       // seq len
constexpr int BS = 1024;     // NB*SS
constexpr int NN = 500;      // nodes
constexpr int FF = 32;       // gat out features
constexpr int EE = 8000;     // edges (without self loops)
constexpr int ET = 8500;     // edges + self loops
constexpr int KK = 16000;    // NN*FF  (lstm input size)
constexpr int HH = 128;      // lstm hidden
constexpr int GG = 512;      // 4*HH
constexpr int KS = 8;        // K-split for the big GEMM (250 BK-steps -> 32,32,31*6)

typedef __attribute__((ext_vector_type(8))) short short8;
typedef __attribute__((ext_vector_type(4))) float f32x4;

__device__ __forceinline__ void gload_lds16(const void* g, void* l) {
    __builtin_amdgcn_global_load_lds((const __attribute__((address_space(1))) void*)g,
                                     (__attribute__((address_space(3))) void*)l, 16, 0, 0);
}

// ---------------- prep kernels ----------------

// xt[n][bs] = x[bs][n]   (x is [B,S,N] row-major, bs = b*S+s)
__global__ void k_transpose_x(const float* __restrict__ x, float* __restrict__ xt) {
    __shared__ float tile[32][33];
    int n0 = blockIdx.x * 32, bs0 = blockIdx.y * 32;
    int tx = threadIdx.x, ty = threadIdx.y;  // 32 x 8
#pragma unroll
    for (int i = 0; i < 4; ++i) {
        int n = n0 + tx, bs = bs0 + ty + i * 8;
        tile[ty + i * 8][tx] = (n < NN) ? x[bs * NN + n] : 0.f;
    }
    __syncthreads();
#pragma unroll
    for (int i = 0; i < 4; ++i) {
        int n = n0 + ty + i * 8, bs = bs0 + tx;
        if (n < NN) xt[n * BS + bs] = tile[tx][ty + i * 8];
    }
}

// w_hh_t[j][g] = w_hh[g][j]   (512x128 -> 128x512)
__global__ void k_whh_t(const float* __restrict__ whh, float* __restrict__ wt) {
    int idx = blockIdx.x * 256 + threadIdx.x;  // 65536 total
    int j = idx >> 9, g = idx & 511;
    wt[idx] = whh[g * HH + j];
}

// w_ih -> hi/lo bf16 planes, pre-swizzled per 64k-block so that linear
// global_load_lds staging yields the XOR-swizzled LDS image.
// w_swz[g][blk][sl(8 bf16)] = w_ih[g][blk][(sl ^ (g&7))*8 ..]
__global__ __launch_bounds__(256) void k_prep_w(const float* __restrict__ w_ih,
                                                ushort* __restrict__ w_hi,
                                                ushort* __restrict__ w_lo) {
    int id = blockIdx.x * 256 + threadIdx.x;  // [0, 2048) ; 2000 used
    if (id >= 2000) return;
    int g = blockIdx.y;           // 512
    int blk = id >> 3, sl = id & 7;
    int srcc = sl ^ (g & 7);
    const float* src = w_ih + (size_t)g * KK + blk * 64 + srcc * 8;
    float4 v0 = *(const float4*)src;
    float4 v1 = *(const float4*)(src + 4);
    float v[8] = {v0.x, v0.y, v0.z, v0.w, v1.x, v1.y, v1.z, v1.w};
    union { ushort u[8]; uint4 q; } hi, lo;
#pragma unroll
    for (int j = 0; j < 8; ++j) {
        __hip_bfloat16 hb = __float2bfloat16(v[j]);
        float hf = __bfloat162float(hb);
        __hip_bfloat16 lb = __float2bfloat16(v[j] - hf);
        hi.u[j] = *reinterpret_cast<ushort*>(&hb);
        lo.u[j] = *reinterpret_cast<ushort*>(&lb);
    }
    size_t off = (size_t)g * KK + blk * 64 + sl * 8;
    *(uint4*)(w_hi + off) = hi.q;
    *(uint4*)(w_lo + off) = lo.q;
}

// count in-degrees (incl self loops), exclusive-scan -> offsets[501], cursor, and ws/wd scalars
__global__ void k_count_scan(const int* __restrict__ ei,
                             const float* __restrict__ gat_w, const float* __restrict__ a_src,
                             const float* __restrict__ a_dst,
                             int* __restrict__ offsets, int* __restrict__ cursor,
                             float* __restrict__ scal) {
    __shared__ int cnt[512];
    __shared__ int sc[2][512];
    int t = threadIdx.x;  // 512 threads
    cnt[t] = 0;
    __syncthreads();
    for (int e = t; e < ET; e += 512) {
        int d = (e < EE) ? ei[EE + e] : (e - EE);
        atomicAdd(&cnt[d], 1);
    }
    __syncthreads();
    sc[0][t] = cnt[t];
    __syncthreads();
    int pb = 0;
    for (int off = 1; off < 512; off <<= 1) {
        int v = sc[pb][t];
        if (t >= off) v += sc[pb][t - off];
        sc[pb ^ 1][t] = v;
        pb ^= 1;
        __syncthreads();
    }
    int inc = sc[pb][t];
    int excl = inc - cnt[t];
    if (t <= NN) offsets[t] = excl;
    if (t < NN) cursor[t] = excl;
    if (t == 0) {
        float ws = 0.f, wd = 0.f;
        for (int f = 0; f < FF; ++f) {
            ws += gat_w[f] * a_src[f];
            wd += gat_w[f] * a_dst[f];
        }
        scal[0] = ws;
        scal[1] = wd;
    }
}

// scatter edge sources into dst-sorted buckets
__global__ void k_scatter(const int* __restrict__ ei, int* __restrict__ cursor,
                          int* __restrict__ esrc) {
    int e = blockIdx.x * 256 + threadIdx.x;
    if (e >= ET) return;
    int sidx = (e < EE) ? ei[e] : (e - EE);
    int d = (e < EE) ? ei[EE + e] : (e - EE);
    int pos = atomicAdd(&cursor[d], 1);
    esrc[pos] = sidx;
}

// ---------------- GAT: per-(n,bs) edge softmax -> s[n][bs] ----------------
__global__ void k_gat(const float* __restrict__ xt, const int* __restrict__ offsets,
                      const int* __restrict__ esrc, const float* __restrict__ scal,
                      float* __restrict__ s) {
    int n = blockIdx.y;
    int bs = blockIdx.x * 256 + threadIdx.x;
    float ws = scal[0], wd = scal[1];
    float xd = xt[n * BS + bs];
    float wdxd = wd * xd;
    int e0 = offsets[n], e1 = offsets[n + 1];
    float m = -1e30f, den = 0.f, num = 0.f;
    for (int j = e0; j < e1; ++j) {
        int sidx = esrc[j];  // uniform across wave
        float xs = xt[sidx * BS + bs];
        float z = ws * xs + wdxd;
        float l = (z > 0.f) ? z : 0.2f * z;  // leaky_relu 0.2
        if (l > m) {
            float r = __expf(m - l);
            den *= r;
            num *= r;
            m = l;
        }
        float p = __expf(l - m);
        den += p;
        num += p * xs;
    }
    s[n * BS + bs] = num / den;
}

// ---------------- big GEMM via bf16x3 MFMA ----------------
// C[bs][g] = sum_k relu(s[k/32][bs]*w[k%32]+b[k%32]) * w_ih[g][k]
// grid (8 bm, 8 bn, 8 ks); 256 thr = 4 waves (2x2); wave tile 64(bs) x 32(g); BK=64.
__global__ __launch_bounds__(256, 2) void k_gemm_mfma(
    const ushort* __restrict__ w_hi, const ushort* __restrict__ w_lo,
    const float* __restrict__ s, const float* __restrict__ gat_w,
    const float* __restrict__ gat_b, float* __restrict__ G2) {
    __shared__ __align__(16) ushort Bs[2][2][64 * 64];  // [buf][hi/lo][g][k] (swizzled image)
    __shared__ float s_lds[2][2][128];                  // [buf][node][bs_local]

    int tid = threadIdx.x;
    int lane = tid & 63;
    int w = tid >> 6;
    int wm = w >> 1, wn = w & 1;
    int bm = blockIdx.x, bn = blockIdx.y, ks = blockIdx.z;
    int bs0 = bm * 128, g0 = bn * 64;
    int step0 = ks * 31 + (ks < 2 ? ks : 2);
    int nst = (ks < 2) ? 32 : 31;

    // per-lane gat affine params for this lane's 8 k-slots
    int fbase = (lane >> 4) * 8;
    float w8[8], b8[8];
#pragma unroll
    for (int j = 0; j < 8; ++j) {
        w8[j] = gat_w[fbase + j];
        b8[j] = gat_b[fbase + j];
    }

    f32x4 acc[4][2] = {};

    auto stageB = [&](int buf, int stepg) {
        // 16 x 1KB global_load_lds; wave w issues q = w*4 .. w*4+3
#pragma unroll
        for (int qq = 0; qq < 4; ++qq) {
            int q = w * 4 + qq;
            int half = q >> 3;  // 0=hi 1=lo
            int sub = q & 7;    // 8-row group
            int row_local = sub * 8 + (lane >> 3);
            int sl = lane & 7;
            const ushort* srcp = (half ? w_lo : w_hi) +
                                 (size_t)(g0 + row_local) * KK + stepg * 64 + sl * 8;
            gload_lds16(srcp, &Bs[buf][half][sub * 512]);
        }
        // stage s rows for the 2 nodes of this step
        int row = tid >> 7, col = tid & 127;
        int n = 2 * stepg + row;
        s_lds[buf][row][col] = s[n * BS + bs0 + col];
    };

    auto compute = [&](int buf) {
#pragma unroll
        for (int kh = 0; kh < 2; ++kh) {
            short8 bh[2], bl[2];
#pragma unroll
            for (int fn = 0; fn < 2; ++fn) {
                int grow = wn * 32 + fn * 16 + (lane & 15);
                int c = kh * 4 + (lane >> 4);
                int slot = c ^ (grow & 7);
                bh[fn] = *(const short8*)&Bs[buf][0][grow * 64 + slot * 8];
                bl[fn] = *(const short8*)&Bs[buf][1][grow * 64 + slot * 8];
            }
#pragma unroll
            for (int fm = 0; fm < 4; ++fm) {
                float sval = s_lds[buf][kh][wm * 64 + fm * 16 + (lane & 15)];
                short8 ah, al;
#pragma unroll
                for (int j = 0; j < 8; ++j) {
                    float t = fmaf(sval, w8[j], b8[j]);
                    t = t > 0.f ? t : 0.f;
                    __hip_bfloat16 hb = __float2bfloat16(t);
                    float hf = __bfloat162float(hb);
                    __hip_bfloat16 lb = __float2bfloat16(t - hf);
                    ah[j] = (short)*reinterpret_cast<ushort*>(&hb);
                    al[j] = (short)*reinterpret_cast<ushort*>(&lb);
                }
#pragma unroll
                for (int fn = 0; fn < 2; ++fn) {
                    acc[fm][fn] = __builtin_amdgcn_mfma_f32_16x16x32_bf16(ah, bh[fn], acc[fm][fn], 0, 0, 0);
                    acc[fm][fn] = __builtin_amdgcn_mfma_f32_16x16x32_bf16(ah, bl[fn], acc[fm][fn], 0, 0, 0);
                    acc[fm][fn] = __builtin_amdgcn_mfma_f32_16x16x32_bf16(al, bh[fn], acc[fm][fn], 0, 0, 0);
                }
            }
        }
    };

    stageB(0, step0);
    __syncthreads();
    for (int t = 0; t < nst; ++t) {
        if (t + 1 < nst) stageB((t + 1) & 1, step0 + t + 1);
        compute(t & 1);
        __syncthreads();
    }

    // epilogue: C/D frag layout col=lane&15, row=(lane>>4)*4+r
    float* Gks = G2 + (size_t)ks * BS * GG;
#pragma unroll
    for (int fm = 0; fm < 4; ++fm) {
#pragma unroll
        for (int fn = 0; fn < 2; ++fn) {
            int bs = bs0 + wm * 64 + fm * 16 + ((lane >> 4) << 2);
            int g = g0 + wn * 32 + fn * 16 + (lane & 15);
            float* base = Gks + (size_t)bs * GG + g;
#pragma unroll
            for (int r = 0; r < 4; ++r) base[r * GG] = acc[fm][fn][r];
        }
    }
}

// ---------------- LSTM (16 independent chains) + head ----------------
__global__ __launch_bounds__(512) void k_lstm_head(const float* __restrict__ G2,
                                                   const float* __restrict__ b_ih,
                                                   const float* __restrict__ b_hh,
                                                   const float* __restrict__ wt,  // [128][512]
                                                   const float* __restrict__ head_w,
                                                   const float* __restrict__ head_b,
                                                   float* __restrict__ out) {
    __shared__ __align__(16) float h_lds[HH];
    __shared__ float gates[GG];
    int tid = threadIdx.x;  // 512
    int b = blockIdx.x;     // 16
    float wreg[HH];
#pragma unroll
    for (int j = 0; j < HH; ++j) wreg[j] = wt[j * GG + tid];
    float bias = b_ih[tid] + b_hh[tid];
    float c = 0.f;
    if (tid < HH) h_lds[tid] = 0.f;
    __syncthreads();
    for (int t = 0; t < SS; ++t) {
        size_t row = (size_t)(b * SS + t) * GG + tid;
        float acc = bias;
#pragma unroll
        for (int p = 0; p < KS; ++p) acc += G2[(size_t)p * BS * GG + row];
        const float4* h4 = (const float4*)h_lds;
#pragma unroll
        for (int j4 = 0; j4 < HH / 4; ++j4) {
            float4 hv = h4[j4];
            acc += wreg[j4 * 4 + 0] * hv.x + wreg[j4 * 4 + 1] * hv.y + wreg[j4 * 4 + 2] * hv.z +
                   wreg[j4 * 4 + 3] * hv.w;
        }
        gates[tid] = acc;
        __syncthreads();
        if (tid < HH) {
            float ig = gates[tid], fg = gates[HH + tid], gg = gates[2 * HH + tid],
                  og = gates[3 * HH + tid];
            float si = 1.f / (1.f + __expf(-ig));
            float sf = 1.f / (1.f + __expf(-fg));
            float so = 1.f / (1.f + __expf(-og));
            c = sf * c + si * tanhf(gg);
            h_lds[tid] = so * tanhf(c);
        }
        __syncthreads();
    }
    if (tid < NN) {
        float acc = head_b[tid];
        const float4* h4 = (const float4*)h_lds;
        const float4* w4 = (const float4*)&head_w[tid * HH];
#pragma unroll
        for (int j4 = 0; j4 < HH / 4; ++j4) {
            float4 hv = h4[j4];
            float4 wv = w4[j4];
            acc += wv.x * hv.x + wv.y * hv.y + wv.z * hv.z + wv.w * hv.w;
        }
        out[b * NN + tid] = acc;
    }
}

// ---------------- launch ----------------
extern "C" void kernel_launch(void* const* d_in, const int* in_sizes, int n_in, void* d_out,
                              int out_size, void* d_ws, size_t ws_size, hipStream_t stream) {
    const float* x = (const float*)d_in[0];
    const int* ei = (const int*)d_in[1];  // integer inputs arrive as int32
    const float* gat_w = (const float*)d_in[2];
    const float* a_src = (const float*)d_in[3];
    const float* a_dst = (const float*)d_in[4];
    const float* gat_b = (const float*)d_in[5];
    const float* w_ih = (const float*)d_in[6];
    const float* w_hh = (const float*)d_in[7];
    const float* b_ih = (const float*)d_in[8];
    const float* b_hh = (const float*)d_in[9];
    const float* head_w = (const float*)d_in[10];
    const float* head_b = (const float*)d_in[11];
    float* out = (float*)d_out;

    char* ws = (char*)d_ws;
    float* xt = (float*)(ws + 0);                    // 2,048,000
    float* s = (float*)(ws + 2048000u);              // 2,048,000
    float* G2 = (float*)(ws + 4096000u);             // 8*1024*512*4 = 16,777,216
    float* wt = (float*)(ws + 20873216u);            // 262,144
    char* base2 = ws + 21135360u;                    // misc 65,536
    int* offsets = (int*)(base2);                    // 501 ints
    int* cursor = (int*)(base2 + 4096);              // 500 ints
    int* esrc = (int*)(base2 + 8192);                // 8500 ints
    float* scal = (float*)(base2 + 45056);           // 2 floats
    ushort* w_hi = (ushort*)(ws + 21200896u);        // 16,384,000
    ushort* w_lo = (ushort*)(ws + 37584896u);        // 16,384,000
    // total ws usage: 53,968,896 bytes

    k_transpose_x<<<dim3(16, 32), dim3(32, 8), 0, stream>>>(x, xt);
    k_whh_t<<<256, 256, 0, stream>>>(w_hh, wt);
    k_prep_w<<<dim3(8, 512), 256, 0, stream>>>(w_ih, w_hi, w_lo);
    k_count_scan<<<1, 512, 0, stream>>>(ei, gat_w, a_src, a_dst, offsets, cursor, scal);
    k_scatter<<<(ET + 255) / 256, 256, 0, stream>>>(ei, cursor, esrc);
    k_gat<<<dim3(BS / 256, NN), 256, 0, stream>>>(xt, offsets, esrc, scal, s);
    k_gemm_mfma<<<dim3(8, 8, 8), 256, 0, stream>>>(w_hi, w_lo, s, gat_w, gat_b, G2);
    k_lstm_head<<<NB, 512, 0, stream>>>(G2, b_ih, b_hh, wt, head_w, head_b, out);
}

// Round 4
// 186.196 us; speedup vs baseline: 2.4519x; 1.7421x over previous
//
#include <hip/hip_runtime.h>
#include <hip/hip_bf16.h>

// ---------------- problem constants ----------------
constexpr int NB = 16;       // batch
constexpr int SS = 64;       // seq len
constexpr int BS = 1024;     // NB*SS
constexpr int NN = 500;      // nodes
constexpr int FF = 32;       // gat out features
constexpr int EE = 8000;     // edges (without self loops)
constexpr int ET = 8500;     // edges + self loops
constexpr int KK = 16000;    // NN*FF  (lstm input size)
constexpr int HH = 128;      // lstm hidden
constexpr int GG = 512;      // 4*HH
constexpr int KS = 8;        // K-split for the big GEMM

typedef __attribute__((ext_vector_type(8))) short short8;
typedef __attribute__((ext_vector_type(4))) float f32x4;

__device__ __forceinline__ void gload_lds16(const void* g, void* l) {
    __builtin_amdgcn_global_load_lds((const __attribute__((address_space(1))) void*)g,
                                     (__attribute__((address_space(3))) void*)l, 16, 0, 0);
}

__device__ __forceinline__ float fast_sigmoid(float x) {
    // 1/(1+e^-x); exp overflow/underflow saturate correctly
    return __builtin_amdgcn_rcpf(1.f + __expf(-x));
}
__device__ __forceinline__ float fast_tanh(float x) {
    float ax = fabsf(x);
    float t = 1.f - 2.f * __builtin_amdgcn_rcpf(1.f + __expf(2.f * ax));
    return copysignf(t, x);
}

// ---------------- prep kernels ----------------

// xt[n][bs] = x[bs][n]   (x is [B,S,N] row-major, bs = b*S+s)
__global__ void k_transpose_x(const float* __restrict__ x, float* __restrict__ xt) {
    __shared__ float tile[32][33];
    int n0 = blockIdx.x * 32, bs0 = blockIdx.y * 32;
    int tx = threadIdx.x, ty = threadIdx.y;  // 32 x 8
#pragma unroll
    for (int i = 0; i < 4; ++i) {
        int n = n0 + tx, bs = bs0 + ty + i * 8;
        tile[ty + i * 8][tx] = (n < NN) ? x[bs * NN + n] : 0.f;
    }
    __syncthreads();
#pragma unroll
    for (int i = 0; i < 4; ++i) {
        int n = n0 + ty + i * 8, bs = bs0 + tx;
        if (n < NN) xt[n * BS + bs] = tile[tx][ty + i * 8];
    }
}

// w_hh_t[j][g] = w_hh[g][j]   (512x128 -> 128x512)
__global__ void k_whh_t(const float* __restrict__ whh, float* __restrict__ wt) {
    int idx = blockIdx.x * 256 + threadIdx.x;  // 65536 total
    int j = idx >> 9, g = idx & 511;
    wt[idx] = whh[g * HH + j];
}

// w_ih -> hi/lo bf16 planes, pre-swizzled per 64k-block (see k_gemm_mfma reads)
__global__ __launch_bounds__(256) void k_prep_w(const float* __restrict__ w_ih,
                                                ushort* __restrict__ w_hi,
                                                ushort* __restrict__ w_lo) {
    int id = blockIdx.x * 256 + threadIdx.x;  // [0, 2048) ; 2000 used
    if (id >= 2000) return;
    int g = blockIdx.y;  // 512
    int blk = id >> 3, sl = id & 7;
    int srcc = sl ^ (g & 7);
    const float* src = w_ih + (size_t)g * KK + blk * 64 + srcc * 8;
    float4 v0 = *(const float4*)src;
    float4 v1 = *(const float4*)(src + 4);
    float v[8] = {v0.x, v0.y, v0.z, v0.w, v1.x, v1.y, v1.z, v1.w};
    union { ushort u[8]; uint4 q; } hi, lo;
#pragma unroll
    for (int j = 0; j < 8; ++j) {
        __hip_bfloat16 hb = __float2bfloat16(v[j]);
        float hf = __bfloat162float(hb);
        __hip_bfloat16 lb = __float2bfloat16(v[j] - hf);
        hi.u[j] = *reinterpret_cast<ushort*>(&hb);
        lo.u[j] = *reinterpret_cast<ushort*>(&lb);
    }
    size_t off = (size_t)g * KK + blk * 64 + sl * 8;
    *(uint4*)(w_hi + off) = hi.q;
    *(uint4*)(w_lo + off) = lo.q;
}

// count in-degrees, scan -> offsets/cursor, and ws/wd scalars
__global__ void k_count_scan(const int* __restrict__ ei,
                             const float* __restrict__ gat_w, const float* __restrict__ a_src,
                             const float* __restrict__ a_dst,
                             int* __restrict__ offsets, int* __restrict__ cursor,
                             float* __restrict__ scal) {
    __shared__ int cnt[512];
    __shared__ int sc[2][512];
    int t = threadIdx.x;  // 512 threads
    cnt[t] = 0;
    __syncthreads();
    for (int e = t; e < ET; e += 512) {
        int d = (e < EE) ? ei[EE + e] : (e - EE);
        atomicAdd(&cnt[d], 1);
    }
    __syncthreads();
    sc[0][t] = cnt[t];
    __syncthreads();
    int pb = 0;
    for (int off = 1; off < 512; off <<= 1) {
        int v = sc[pb][t];
        if (t >= off) v += sc[pb][t - off];
        sc[pb ^ 1][t] = v;
        pb ^= 1;
        __syncthreads();
    }
    int inc = sc[pb][t];
    int excl = inc - cnt[t];
    if (t <= NN) offsets[t] = excl;
    if (t < NN) cursor[t] = excl;
    if (t == 0) {
        float ws = 0.f, wd = 0.f;
        for (int f = 0; f < FF; ++f) {
            ws += gat_w[f] * a_src[f];
            wd += gat_w[f] * a_dst[f];
        }
        scal[0] = ws;
        scal[1] = wd;
    }
}

// scatter edge sources into dst-sorted buckets
__global__ void k_scatter(const int* __restrict__ ei, int* __restrict__ cursor,
                          int* __restrict__ esrc) {
    int e = blockIdx.x * 256 + threadIdx.x;
    if (e >= ET) return;
    int sidx = (e < EE) ? ei[e] : (e - EE);
    int d = (e < EE) ? ei[EE + e] : (e - EE);
    int pos = atomicAdd(&cursor[d], 1);
    esrc[pos] = sidx;
}

// ---------------- GAT: per-(n,bs) edge softmax -> s[n][bs] ----------------
__global__ void k_gat(const float* __restrict__ xt, const int* __restrict__ offsets,
                      const int* __restrict__ esrc, const float* __restrict__ scal,
                      float* __restrict__ s) {
    int n = blockIdx.y;
    int bs = blockIdx.x * 256 + threadIdx.x;
    float ws = scal[0], wd = scal[1];
    float xd = xt[n * BS + bs];
    float wdxd = wd * xd;
    int e0 = offsets[n], e1 = offsets[n + 1];
    float m = -1e30f, den = 0.f, num = 0.f;
    for (int j = e0; j < e1; ++j) {
        int sidx = esrc[j];  // uniform across wave
        float xs = xt[sidx * BS + bs];
        float z = ws * xs + wdxd;
        float l = (z > 0.f) ? z : 0.2f * z;  // leaky_relu 0.2
        if (l > m) {
            float r = __expf(m - l);
            den *= r;
            num *= r;
            m = l;
        }
        float p = __expf(l - m);
        den += p;
        num += p * xs;
    }
    s[n * BS + bs] = num / den;
}

// ---------------- big GEMM via bf16x3 MFMA ----------------
__global__ __launch_bounds__(256, 2) void k_gemm_mfma(
    const ushort* __restrict__ w_hi, const ushort* __restrict__ w_lo,
    const float* __restrict__ s, const float* __restrict__ gat_w,
    const float* __restrict__ gat_b, float* __restrict__ G2) {
    __shared__ __align__(16) ushort Bs[2][2][64 * 64];  // [buf][hi/lo][g][k] (swizzled image)
    __shared__ float s_lds[2][2][128];                  // [buf][node][bs_local]

    int tid = threadIdx.x;
    int lane = tid & 63;
    int w = tid >> 6;
    int wm = w >> 1, wn = w & 1;
    int bm = blockIdx.x, bn = blockIdx.y, ks = blockIdx.z;
    int bs0 = bm * 128, g0 = bn * 64;
    int step0 = ks * 31 + (ks < 2 ? ks : 2);
    int nst = (ks < 2) ? 32 : 31;

    int fbase = (lane >> 4) * 8;
    float w8[8], b8[8];
#pragma unroll
    for (int j = 0; j < 8; ++j) {
        w8[j] = gat_w[fbase + j];
        b8[j] = gat_b[fbase + j];
    }

    f32x4 acc[4][2] = {};

    auto stageB = [&](int buf, int stepg) {
#pragma unroll
        for (int qq = 0; qq < 4; ++qq) {
            int q = w * 4 + qq;
            int half = q >> 3;
            int sub = q & 7;
            int row_local = sub * 8 + (lane >> 3);
            int sl = lane & 7;
            const ushort* srcp = (half ? w_lo : w_hi) +
                                 (size_t)(g0 + row_local) * KK + stepg * 64 + sl * 8;
            gload_lds16(srcp, &Bs[buf][half][sub * 512]);
        }
        int row = tid >> 7, col = tid & 127;
        int n = 2 * stepg + row;
        s_lds[buf][row][col] = s[n * BS + bs0 + col];
    };

    auto compute = [&](int buf) {
#pragma unroll
        for (int kh = 0; kh < 2; ++kh) {
            short8 bh[2], bl[2];
#pragma unroll
            for (int fn = 0; fn < 2; ++fn) {
                int grow = wn * 32 + fn * 16 + (lane & 15);
                int c = kh * 4 + (lane >> 4);
                int slot = c ^ (grow & 7);
                bh[fn] = *(const short8*)&Bs[buf][0][grow * 64 + slot * 8];
                bl[fn] = *(const short8*)&Bs[buf][1][grow * 64 + slot * 8];
            }
#pragma unroll
            for (int fm = 0; fm < 4; ++fm) {
                float sval = s_lds[buf][kh][wm * 64 + fm * 16 + (lane & 15)];
                short8 ah, al;
#pragma unroll
                for (int j = 0; j < 8; ++j) {
                    float t = fmaf(sval, w8[j], b8[j]);
                    t = t > 0.f ? t : 0.f;
                    __hip_bfloat16 hb = __float2bfloat16(t);
                    float hf = __bfloat162float(hb);
                    __hip_bfloat16 lb = __float2bfloat16(t - hf);
                    ah[j] = (short)*reinterpret_cast<ushort*>(&hb);
                    al[j] = (short)*reinterpret_cast<ushort*>(&lb);
                }
#pragma unroll
                for (int fn = 0; fn < 2; ++fn) {
                    acc[fm][fn] = __builtin_amdgcn_mfma_f32_16x16x32_bf16(ah, bh[fn], acc[fm][fn], 0, 0, 0);
                    acc[fm][fn] = __builtin_amdgcn_mfma_f32_16x16x32_bf16(ah, bl[fn], acc[fm][fn], 0, 0, 0);
                    acc[fm][fn] = __builtin_amdgcn_mfma_f32_16x16x32_bf16(al, bh[fn], acc[fm][fn], 0, 0, 0);
                }
            }
        }
    };

    stageB(0, step0);
    __syncthreads();
    for (int t = 0; t < nst; ++t) {
        if (t + 1 < nst) stageB((t + 1) & 1, step0 + t + 1);
        compute(t & 1);
        __syncthreads();
    }

    float* Gks = G2 + (size_t)ks * BS * GG;
#pragma unroll
    for (int fm = 0; fm < 4; ++fm) {
#pragma unroll
        for (int fn = 0; fn < 2; ++fn) {
            int bs = bs0 + wm * 64 + fm * 16 + ((lane >> 4) << 2);
            int g = g0 + wn * 32 + fn * 16 + (lane & 15);
            float* base = Gks + (size_t)bs * GG + g;
#pragma unroll
            for (int r = 0; r < 4; ++r) base[r * GG] = acc[fm][fn][r];
        }
    }
}

// ---------------- reduce K-split partials + biases -> Xg[bs][512] ----------------
__global__ __launch_bounds__(256) void k_reduce(const float* __restrict__ G2,
                                                const float* __restrict__ b_ih,
                                                const float* __restrict__ b_hh,
                                                float* __restrict__ Xg) {
    int idx = blockIdx.x * 256 + threadIdx.x;  // 131072 float4 slots
    int e = idx * 4;
    int g = e & (GG - 1);
    float4 acc = *(const float4*)&b_ih[g];
    float4 bh = *(const float4*)&b_hh[g];
    acc.x += bh.x; acc.y += bh.y; acc.z += bh.z; acc.w += bh.w;
#pragma unroll
    for (int p = 0; p < KS; ++p) {
        float4 v = *(const float4*)&G2[(size_t)p * BS * GG + e];
        acc.x += v.x; acc.y += v.y; acc.z += v.z; acc.w += v.w;
    }
    *(float4*)&Xg[e] = acc;
}

// ---------------- LSTM (16 chains; 1024 thr: gate g x k-half) + head ----------------
__global__ __launch_bounds__(1024) void k_lstm_head(const float* __restrict__ Xg,
                                                    const float* __restrict__ wt,  // [128][512]
                                                    const float* __restrict__ head_w,
                                                    const float* __restrict__ head_b,
                                                    float* __restrict__ out) {
    __shared__ __align__(16) float h_lds[HH];
    __shared__ float part[1024];
    int tid = threadIdx.x;
    int b = blockIdx.x;  // 16
    int half = tid >> 9; // 0: k 0..63, 1: k 64..127
    int g = tid & 511;

    float wr[64];
#pragma unroll
    for (int k = 0; k < 64; ++k) wr[k] = wt[(half * 64 + k) * GG + g];

    float xg_next = 0.f;
    if (half == 0) xg_next = Xg[(size_t)(b * SS) * GG + g];

    float c = 0.f;
    if (tid < HH) h_lds[tid] = 0.f;
    __syncthreads();

    for (int t = 0; t < SS; ++t) {
        float a0 = 0.f, a1 = 0.f, a2 = 0.f, a3 = 0.f;
        const float4* h4 = (const float4*)&h_lds[half * 64];
#pragma unroll
        for (int j4 = 0; j4 < 16; ++j4) {
            float4 hv = h4[j4];
            a0 = fmaf(wr[j4 * 4 + 0], hv.x, a0);
            a1 = fmaf(wr[j4 * 4 + 1], hv.y, a1);
            a2 = fmaf(wr[j4 * 4 + 2], hv.z, a2);
            a3 = fmaf(wr[j4 * 4 + 3], hv.w, a3);
        }
        float sum = (a0 + a1) + (a2 + a3);
        if (half == 0) sum += xg_next;
        part[tid] = sum;
        // prefetch next step's x-projection (independent of h)
        if (half == 0 && t + 1 < SS) xg_next = Xg[(size_t)(b * SS + t + 1) * GG + g];
        __syncthreads();
        if (tid < HH) {
            int j = tid;
            float ig = part[j] + part[512 + j];
            float fg = part[128 + j] + part[640 + j];
            float gg = part[256 + j] + part[768 + j];
            float og = part[384 + j] + part[896 + j];
            float si = fast_sigmoid(ig);
            float sf = fast_sigmoid(fg);
            float so = fast_sigmoid(og);
            c = sf * c + si * fast_tanh(gg);
            h_lds[j] = so * fast_tanh(c);
        }
        __syncthreads();
    }
    if (tid < NN) {
        float acc = head_b[tid];
        const float4* h4 = (const float4*)h_lds;
        const float4* w4 = (const float4*)&head_w[tid * HH];
#pragma unroll
        for (int j4 = 0; j4 < HH / 4; ++j4) {
            float4 hv = h4[j4];
            float4 wv = w4[j4];
            acc += wv.x * hv.x + wv.y * hv.y + wv.z * hv.z + wv.w * hv.w;
        }
        out[b * NN + tid] = acc;
    }
}

// ---------------- launch ----------------
extern "C" void kernel_launch(void* const* d_in, const int* in_sizes, int n_in, void* d_out,
                              int out_size, void* d_ws, size_t ws_size, hipStream_t stream) {
    const float* x = (const float*)d_in[0];
    const int* ei = (const int*)d_in[1];  // integer inputs arrive as int32
    const float* gat_w = (const float*)d_in[2];
    const float* a_src = (const float*)d_in[3];
    const float* a_dst = (const float*)d_in[4];
    const float* gat_b = (const float*)d_in[5];
    const float* w_ih = (const float*)d_in[6];
    const float* w_hh = (const float*)d_in[7];
    const float* b_ih = (const float*)d_in[8];
    const float* b_hh = (const float*)d_in[9];
    const float* head_w = (const float*)d_in[10];
    const float* head_b = (const float*)d_in[11];
    float* out = (float*)d_out;

    char* ws = (char*)d_ws;
    float* xt = (float*)(ws + 0);              // 2,048,000 (dead after k_gat)
    float* s = (float*)(ws + 2048000u);        // 2,048,000 (dead after k_gemm)
    float* G2 = (float*)(ws + 4096000u);       // 16,777,216
    float* wt = (float*)(ws + 20873216u);      // 262,144
    char* base2 = ws + 21135360u;              // misc 65,536
    int* offsets = (int*)(base2);
    int* cursor = (int*)(base2 + 4096);
    int* esrc = (int*)(base2 + 8192);
    float* scal = (float*)(base2 + 45056);
    ushort* w_hi = (ushort*)(ws + 21200896u);  // 16,384,000
    ushort* w_lo = (ushort*)(ws + 37584896u);  // 16,384,000
    float* Xg = (float*)(ws + 0);              // 2,097,152 — overlaps xt+s head (both dead
                                               // by the time k_reduce runs; stream-ordered)

    k_transpose_x<<<dim3(16, 32), dim3(32, 8), 0, stream>>>(x, xt);
    k_whh_t<<<256, 256, 0, stream>>>(w_hh, wt);
    k_prep_w<<<dim3(8, 512), 256, 0, stream>>>(w_ih, w_hi, w_lo);
    k_count_scan<<<1, 512, 0, stream>>>(ei, gat_w, a_src, a_dst, offsets, cursor, scal);
    k_scatter<<<(ET + 255) / 256, 256, 0, stream>>>(ei, cursor, esrc);
    k_gat<<<dim3(BS / 256, NN), 256, 0, stream>>>(xt, offsets, esrc, scal, s);
    k_gemm_mfma<<<dim3(8, 8, 8), 256, 0, stream>>>(w_hi, w_lo, s, gat_w, gat_b, G2);
    k_reduce<<<512, 256, 0, stream>>>(G2, b_ih, b_hh, Xg);
    k_lstm_head<<<NB, 1024, 0, stream>>>(Xg, wt, head_w, head_b, out);
}

// Round 5
// 145.065 us; speedup vs baseline: 3.1471x; 1.2835x over previous
//
#include <hip/hip_runtime.h>
#include <hip/hip_bf16.h>
#include <hip/hip_fp16.h>

// ---------------- problem constants ----------------
constexpr int NB = 16;       // batch
constexpr int SS = 64;       // seq len
constexpr int BS = 1024;     // NB*SS
constexpr int NN = 500;      // nodes
constexpr int FF = 32;       // gat out features
constexpr int EE = 8000;     // edges (without self loops)
constexpr int ET = 8500;     // edges + self loops
constexpr int KK = 16000;    // NN*FF  (lstm input size)
constexpr int HH = 128;      // lstm hidden
constexpr int GG = 512;      // 4*HH
constexpr int KS = 16;       // K-split for the big GEMM (250 steps of 64k)

typedef __attribute__((ext_vector_type(8))) _Float16 f16x8;
typedef __attribute__((ext_vector_type(4))) float f32x4;

__device__ __forceinline__ void gload_lds16(const void* g, void* l) {
    __builtin_amdgcn_global_load_lds((const __attribute__((address_space(1))) void*)g,
                                     (__attribute__((address_space(3))) void*)l, 16, 0, 0);
}

__device__ __forceinline__ float fast_sigmoid(float x) {
    return __builtin_amdgcn_rcpf(1.f + __expf(-x));
}
__device__ __forceinline__ float fast_tanh(float x) {
    float ax = fabsf(x);
    float t = 1.f - 2.f * __builtin_amdgcn_rcpf(1.f + __expf(2.f * ax));
    return copysignf(t, x);
}

// ---------------- fused prep: transpose_x | whh_t | w_ih->fp16 swizzled ----------------
__global__ __launch_bounds__(256) void k_prep(const float* __restrict__ x, float* __restrict__ xt,
                                              const float* __restrict__ whh, float* __restrict__ wt,
                                              const float* __restrict__ w_ih,
                                              _Float16* __restrict__ w_h) {
    __shared__ float tile[32][33];
    int bid = blockIdx.x;
    int tid = threadIdx.x;
    if (bid < 512) {
        // xt[n][bs] = x[bs][n]
        int n0 = (bid & 15) * 32, bs0 = (bid >> 4) * 32;
        int tx = tid & 31, ty = tid >> 5;  // 32 x 8
#pragma unroll
        for (int i = 0; i < 4; ++i) {
            int n = n0 + tx, bs = bs0 + ty + i * 8;
            tile[ty + i * 8][tx] = (n < NN) ? x[bs * NN + n] : 0.f;
        }
        __syncthreads();
#pragma unroll
        for (int i = 0; i < 4; ++i) {
            int n = n0 + ty + i * 8, bs = bs0 + tx;
            if (n < NN) xt[n * BS + bs] = tile[tx][ty + i * 8];
        }
    } else if (bid < 768) {
        // wt[j][g] = whh[g][j]
        int idx = (bid - 512) * 256 + tid;
        wt[idx] = whh[(idx & 511) * HH + (idx >> 9)];
    } else {
        // w_h[g][blk*64 + sl*8 + j] = (fp16) w_ih[g][blk*64 + (sl^(g&7))*8 + j]
        int r = bid - 768;            // 0..4095
        int g = r >> 3;               // 512 rows
        int id = (r & 7) * 256 + tid; // 0..2047, 2000 used
        if (id < 2000) {
            int blk = id >> 3, sl = id & 7;
            int srcc = sl ^ (g & 7);
            const float* src = w_ih + (size_t)g * KK + blk * 64 + srcc * 8;
            float4 v0 = *(const float4*)src;
            float4 v1 = *(const float4*)(src + 4);
            union { __half2 h2[4]; uint4 q; } u;
            u.h2[0] = __floats2half2_rn(v0.x, v0.y);
            u.h2[1] = __floats2half2_rn(v0.z, v0.w);
            u.h2[2] = __floats2half2_rn(v1.x, v1.y);
            u.h2[3] = __floats2half2_rn(v1.z, v1.w);
            *(uint4*)(w_h + (size_t)g * KK + blk * 64 + sl * 8) = u.q;
        }
    }
}

// ---------------- fused graph build: count -> scan -> scatter (1 block) ----------------
__global__ __launch_bounds__(512) void k_graph(const int* __restrict__ ei,
                                               const float* __restrict__ gat_w,
                                               const float* __restrict__ a_src,
                                               const float* __restrict__ a_dst,
                                               int* __restrict__ offsets,
                                               int* __restrict__ esrc,
                                               float* __restrict__ scal) {
    __shared__ int cnt[512];
    __shared__ int sc[2][512];
    __shared__ int cur[512];
    int t = threadIdx.x;  // 512
    cnt[t] = 0;
    __syncthreads();
    for (int e = t; e < ET; e += 512) {
        int d = (e < EE) ? ei[EE + e] : (e - EE);
        atomicAdd(&cnt[d], 1);
    }
    __syncthreads();
    sc[0][t] = cnt[t];
    __syncthreads();
    int pb = 0;
    for (int off = 1; off < 512; off <<= 1) {
        int v = sc[pb][t];
        if (t >= off) v += sc[pb][t - off];
        sc[pb ^ 1][t] = v;
        pb ^= 1;
        __syncthreads();
    }
    int excl = sc[pb][t] - cnt[t];
    if (t <= NN) offsets[t] = excl;
    cur[t] = excl;
    if (t == 0) {
        float ws = 0.f, wd = 0.f;
        for (int f = 0; f < FF; ++f) {
            ws += gat_w[f] * a_src[f];
            wd += gat_w[f] * a_dst[f];
        }
        scal[0] = ws;
        scal[1] = wd;
    }
    __syncthreads();
    for (int e = t; e < ET; e += 512) {
        int sidx = (e < EE) ? ei[e] : (e - EE);
        int d = (e < EE) ? ei[EE + e] : (e - EE);
        int pos = atomicAdd(&cur[d], 1);
        esrc[pos] = sidx;
    }
}

// ---------------- GAT: per-(n,bs) edge softmax -> s[n][bs] ----------------
__global__ void k_gat(const float* __restrict__ xt, const int* __restrict__ offsets,
                      const int* __restrict__ esrc, const float* __restrict__ scal,
                      float* __restrict__ s) {
    int n = blockIdx.y;
    int bs = blockIdx.x * 256 + threadIdx.x;
    float ws = scal[0], wd = scal[1];
    float xd = xt[n * BS + bs];
    float wdxd = wd * xd;
    int e0 = offsets[n], e1 = offsets[n + 1];
    float m = -1e30f, den = 0.f, num = 0.f;
    for (int j = e0; j < e1; ++j) {
        int sidx = esrc[j];  // uniform across wave
        float xs = xt[sidx * BS + bs];
        float z = ws * xs + wdxd;
        float l = (z > 0.f) ? z : 0.2f * z;  // leaky_relu 0.2
        if (l > m) {
            float r = __expf(m - l);
            den *= r;
            num *= r;
            m = l;
        }
        float p = __expf(l - m);
        den += p;
        num += p * xs;
    }
    s[n * BS + bs] = num / den;
}

// ---------------- big GEMM via fp16 MFMA ----------------
// C[bs][g] = sum_k relu(s[k/32][bs]*w[k%32]+b[k%32]) * w_ih[g][k]
// grid (8 bm, 4 bn, 16 ks); 256 thr = 4 waves (2x2); wave tile 64(bs) x 64(g); BK=64.
__global__ __launch_bounds__(256, 2) void k_gemm_mfma(
    const _Float16* __restrict__ w_h, const float* __restrict__ s,
    const float* __restrict__ gat_w, const float* __restrict__ gat_b,
    float* __restrict__ G2) {
    __shared__ __align__(16) _Float16 Bs[2][128 * 64];  // [buf][g][k] swizzled image, 16 KB each
    __shared__ float s_lds[2][2][128];                  // [buf][node][bs_local]

    int tid = threadIdx.x;
    int lane = tid & 63;
    int w = tid >> 6;
    int wm = w >> 1, wn = w & 1;
    int bm = blockIdx.x, bn = blockIdx.y, ks = blockIdx.z;
    int bs0 = bm * 128, g0 = bn * 128;
    int step0 = (ks * 250) >> 4;
    int nst = (((ks + 1) * 250) >> 4) - step0;  // 15 or 16

    // per-lane gat affine params for this lane's 8 k-slots (f = (lane>>4)*8 + j)
    int fbase = (lane >> 4) * 8;
    float w8[8], b8[8];
#pragma unroll
    for (int j = 0; j < 8; ++j) {
        w8[j] = gat_w[fbase + j];
        b8[j] = gat_b[fbase + j];
    }

    f32x4 acc[4][4] = {};

    auto stageB = [&](int buf, int stepg) {
        // 16 x 1KB global_load_lds; wave w issues q = w*4 .. w*4+3
#pragma unroll
        for (int qq = 0; qq < 4; ++qq) {
            int q = w * 4 + qq;            // 16 groups of 8 g-rows
            int row_local = q * 8 + (lane >> 3);
            int sl = lane & 7;
            const _Float16* srcp = w_h + (size_t)(g0 + row_local) * KK + stepg * 64 + sl * 8;
            gload_lds16(srcp, &Bs[buf][q * 512]);
        }
        // stage s rows for the 2 nodes of this step
        int row = tid >> 7, col = tid & 127;
        int n = 2 * stepg + row;
        s_lds[buf][row][col] = s[n * BS + bs0 + col];
    };

    auto compute = [&](int buf) {
#pragma unroll
        for (int kh = 0; kh < 2; ++kh) {
            f16x8 bfrag[4];
#pragma unroll
            for (int fn = 0; fn < 4; ++fn) {
                int grow = wn * 64 + fn * 16 + (lane & 15);
                int c = kh * 4 + (lane >> 4);
                int slot = c ^ (grow & 7);
                bfrag[fn] = *(const f16x8*)&Bs[buf][grow * 64 + slot * 8];
            }
#pragma unroll
            for (int fm = 0; fm < 4; ++fm) {
                float sval = s_lds[buf][kh][wm * 64 + fm * 16 + (lane & 15)];
                union { f16x8 v; __half2 h2[4]; } af;
#pragma unroll
                for (int j2 = 0; j2 < 4; ++j2) {
                    float t0 = fmaf(sval, w8[2 * j2], b8[2 * j2]);
                    float t1 = fmaf(sval, w8[2 * j2 + 1], b8[2 * j2 + 1]);
                    t0 = t0 > 0.f ? t0 : 0.f;
                    t1 = t1 > 0.f ? t1 : 0.f;
                    af.h2[j2] = __floats2half2_rn(t0, t1);
                }
#pragma unroll
                for (int fn = 0; fn < 4; ++fn) {
                    acc[fm][fn] =
                        __builtin_amdgcn_mfma_f32_16x16x32_f16(af.v, bfrag[fn], acc[fm][fn], 0, 0, 0);
                }
            }
        }
    };

    stageB(0, step0);
    __syncthreads();
    for (int t = 0; t < nst; ++t) {
        if (t + 1 < nst) stageB((t + 1) & 1, step0 + t + 1);
        compute(t & 1);
        __syncthreads();
    }

    // epilogue: C/D frag layout col=lane&15, row=(lane>>4)*4+r
    float* Gks = G2 + (size_t)ks * BS * GG;
#pragma unroll
    for (int fm = 0; fm < 4; ++fm) {
#pragma unroll
        for (int fn = 0; fn < 4; ++fn) {
            int bs = bs0 + wm * 64 + fm * 16 + ((lane >> 4) << 2);
            int g = g0 + wn * 64 + fn * 16 + (lane & 15);
            float* base = Gks + (size_t)bs * GG + g;
#pragma unroll
            for (int r = 0; r < 4; ++r) base[r * GG] = acc[fm][fn][r];
        }
    }
}

// ---------------- reduce K-split partials + biases -> Xg[bs][512] ----------------
__global__ __launch_bounds__(256) void k_reduce(const float* __restrict__ G2,
                                                const float* __restrict__ b_ih,
                                                const float* __restrict__ b_hh,
                                                float* __restrict__ Xg) {
    int idx = blockIdx.x * 256 + threadIdx.x;  // 131072 float4 slots
    int e = idx * 4;
    int g = e & (GG - 1);
    float4 acc = *(const float4*)&b_ih[g];
    float4 bh = *(const float4*)&b_hh[g];
    acc.x += bh.x; acc.y += bh.y; acc.z += bh.z; acc.w += bh.w;
#pragma unroll
    for (int p = 0; p < KS; ++p) {
        float4 v = *(const float4*)&G2[(size_t)p * BS * GG + e];
        acc.x += v.x; acc.y += v.y; acc.z += v.z; acc.w += v.w;
    }
    *(float4*)&Xg[e] = acc;
}

// ---------------- LSTM (16 chains; 1024 thr: gate g x k-half) + head ----------------
__global__ __launch_bounds__(1024) void k_lstm_head(const float* __restrict__ Xg,
                                                    const float* __restrict__ wt,  // [128][512]
                                                    const float* __restrict__ head_w,
                                                    const float* __restrict__ head_b,
                                                    float* __restrict__ out) {
    __shared__ __align__(16) float h_lds[HH];
    __shared__ float part[1024];
    int tid = threadIdx.x;
    int b = blockIdx.x;  // 16
    int half = tid >> 9; // 0: k 0..63, 1: k 64..127
    int g = tid & 511;

    float wr[64];
#pragma unroll
    for (int k = 0; k < 64; ++k) wr[k] = wt[(half * 64 + k) * GG + g];

    float xg_next = 0.f;
    if (half == 0) xg_next = Xg[(size_t)(b * SS) * GG + g];

    float c = 0.f;
    if (tid < HH) h_lds[tid] = 0.f;
    __syncthreads();

    for (int t = 0; t < SS; ++t) {
        float a0 = 0.f, a1 = 0.f, a2 = 0.f, a3 = 0.f;
        const float4* h4 = (const float4*)&h_lds[half * 64];
#pragma unroll
        for (int j4 = 0; j4 < 16; ++j4) {
            float4 hv = h4[j4];
            a0 = fmaf(wr[j4 * 4 + 0], hv.x, a0);
            a1 = fmaf(wr[j4 * 4 + 1], hv.y, a1);
            a2 = fmaf(wr[j4 * 4 + 2], hv.z, a2);
            a3 = fmaf(wr[j4 * 4 + 3], hv.w, a3);
        }
        float sum = (a0 + a1) + (a2 + a3);
        if (half == 0) sum += xg_next;
        part[tid] = sum;
        if (half == 0 && t + 1 < SS) xg_next = Xg[(size_t)(b * SS + t + 1) * GG + g];
        __syncthreads();
        if (tid < HH) {
            int j = tid;
            float ig = part[j] + part[512 + j];
            float fg = part[128 + j] + part[640 + j];
            float gg = part[256 + j] + part[768 + j];
            float og = part[384 + j] + part[896 + j];
            float si = fast_sigmoid(ig);
            float sf = fast_sigmoid(fg);
            float so = fast_sigmoid(og);
            c = sf * c + si * fast_tanh(gg);
            h_lds[j] = so * fast_tanh(c);
        }
        __syncthreads();
    }
    if (tid < NN) {
        float acc = head_b[tid];
        const float4* h4 = (const float4*)h_lds;
        const float4* w4 = (const float4*)&head_w[tid * HH];
#pragma unroll
        for (int j4 = 0; j4 < HH / 4; ++j4) {
            float4 hv = h4[j4];
            float4 wv = w4[j4];
            acc += wv.x * hv.x + wv.y * hv.y + wv.z * hv.z + wv.w * hv.w;
        }
        out[b * NN + tid] = acc;
    }
}

// ---------------- launch ----------------
extern "C" void kernel_launch(void* const* d_in, const int* in_sizes, int n_in, void* d_out,
                              int out_size, void* d_ws, size_t ws_size, hipStream_t stream) {
    const float* x = (const float*)d_in[0];
    const int* ei = (const int*)d_in[1];  // integer inputs arrive as int32
    const float* gat_w = (const float*)d_in[2];
    const float* a_src = (const float*)d_in[3];
    const float* a_dst = (const float*)d_in[4];
    const float* gat_b = (const float*)d_in[5];
    const float* w_ih = (const float*)d_in[6];
    const float* w_hh = (const float*)d_in[7];
    const float* b_ih = (const float*)d_in[8];
    const float* b_hh = (const float*)d_in[9];
    const float* head_w = (const float*)d_in[10];
    const float* head_b = (const float*)d_in[11];
    float* out = (float*)d_out;

    char* ws = (char*)d_ws;
    float* xt = (float*)(ws + 0);                  // 2,048,000 (dead after k_gat)
    float* s = (float*)(ws + 2048000u);            // 2,048,000 (dead after k_gemm)
    float* G2 = (float*)(ws + 4096000u);           // 16*1024*512*4 = 33,554,432
    float* wt = (float*)(ws + 37650432u);          // 262,144
    _Float16* w_h = (_Float16*)(ws + 37912576u);   // 16,384,000
    char* base2 = ws + 54296576u;                  // misc 65,536
    int* offsets = (int*)(base2);
    int* esrc = (int*)(base2 + 4096);
    float* scal = (float*)(base2 + 45056);
    float* Xg = (float*)(ws + 0);                  // 2,097,152 — overlaps xt+s head (both dead
                                                   // by the time k_reduce runs; stream-ordered)

    k_prep<<<4864, 256, 0, stream>>>(x, xt, w_hh, wt, w_ih, w_h);
    k_graph<<<1, 512, 0, stream>>>(ei, gat_w, a_src, a_dst, offsets, esrc, scal);
    k_gat<<<dim3(BS / 256, NN), 256, 0, stream>>>(xt, offsets, esrc, scal, s);
    k_gemm_mfma<<<dim3(8, 4, KS), 256, 0, stream>>>(w_h, s, gat_w, gat_b, G2);
    k_reduce<<<512, 256, 0, stream>>>(G2, b_ih, b_hh, Xg);
    k_lstm_head<<<NB, 1024, 0, stream>>>(Xg, wt, head_w, head_b, out);
}